// Round 1
// baseline (42.919 us; speedup 1.0000x reference)
//
#include <hip/hip_runtime.h>

// BranchRoute: score = sigmoid(x @ W_gate + b), hot_i = score_i > 0.5  <=>  (x·w_i + b_i) > 0
// Outputs (concat, f32): x_0 = hot0 ? x : 0 ; x_1 = hot1 ? x : 0 ; x_comb = x_0 + x_1
// N = 16384 tokens, D = 1024. One block per token.

#define N_TOKENS 16384
#define D_MODEL  1024

__global__ __launch_bounds__(256) void branch_route_kernel(
    const float* __restrict__ x,
    const float* __restrict__ Wg,   // [D_MODEL, 2] row-major: Wg[2*i], Wg[2*i+1]
    const float* __restrict__ bg,   // [2]
    float* __restrict__ out)        // [3 * N * D] : x0 | x1 | xcomb
{
    const int token = blockIdx.x;
    const int tid   = threadIdx.x;          // 0..255, 4 elems each

    // ---- load this thread's 4 elements of the token row (kept in regs) ----
    const float4* xrow = reinterpret_cast<const float4*>(x) + (size_t)token * (D_MODEL / 4);
    float4 v = xrow[tid];

    // ---- gate weights: interleaved (w0[i], w1[i]) pairs ----
    const float4* wv = reinterpret_cast<const float4*>(Wg);
    float4 wa = wv[2 * tid];       // w0[4t], w1[4t], w0[4t+1], w1[4t+1]
    float4 wb = wv[2 * tid + 1];   // w0[4t+2], w1[4t+2], w0[4t+3], w1[4t+3]

    // ---- f64 partial dots (precision: avoid threshold flips near z == 0) ----
    double d0 = (double)v.x * (double)wa.x + (double)v.y * (double)wa.z
              + (double)v.z * (double)wb.x + (double)v.w * (double)wb.z;
    double d1 = (double)v.x * (double)wa.y + (double)v.y * (double)wa.w
              + (double)v.z * (double)wb.y + (double)v.w * (double)wb.w;

    // ---- wave (64-lane) reduction ----
    #pragma unroll
    for (int off = 32; off > 0; off >>= 1) {
        d0 += __shfl_down(d0, off);
        d1 += __shfl_down(d1, off);
    }

    // ---- cross-wave reduction (4 waves) + flag broadcast ----
    __shared__ double s0[4], s1[4];
    __shared__ int flags;
    const int wave = tid >> 6;
    const int lane = tid & 63;
    if (lane == 0) { s0[wave] = d0; s1[wave] = d1; }
    __syncthreads();
    if (tid == 0) {
        double t0 = s0[0] + s0[1] + s0[2] + s0[3] + (double)bg[0];
        double t1 = s1[0] + s1[1] + s1[2] + s1[3] + (double)bg[1];
        flags = (t0 > 0.0 ? 1 : 0) | (t1 > 0.0 ? 2 : 0);
    }
    __syncthreads();
    const int f = flags;

    // ---- write the three outputs (float4 stores, fully coalesced) ----
    const float4 z  = make_float4(0.f, 0.f, 0.f, 0.f);
    const float4 o0 = (f & 1) ? v : z;
    const float4 o1 = (f & 2) ? v : z;
    const float4 oc = make_float4(o0.x + o1.x, o0.y + o1.y, o0.z + o1.z, o0.w + o1.w);

    float4* out0 = reinterpret_cast<float4*>(out) + (size_t)token * (D_MODEL / 4);
    float4* out1 = reinterpret_cast<float4*>(out + (size_t)N_TOKENS * D_MODEL) + (size_t)token * (D_MODEL / 4);
    float4* outc = reinterpret_cast<float4*>(out + 2 * (size_t)N_TOKENS * D_MODEL) + (size_t)token * (D_MODEL / 4);
    out0[tid] = o0;
    out1[tid] = o1;
    outc[tid] = oc;
}

extern "C" void kernel_launch(void* const* d_in, const int* in_sizes, int n_in,
                              void* d_out, int out_size, void* d_ws, size_t ws_size,
                              hipStream_t stream) {
    const float* x  = (const float*)d_in[0];
    const float* Wg = (const float*)d_in[1];
    const float* bg = (const float*)d_in[2];
    float* out      = (float*)d_out;

    branch_route_kernel<<<N_TOKENS, 256, 0, stream>>>(x, Wg, bg, out);
}